// Round 1
// baseline (57.918 us; speedup 1.0000x reference)
//
#include <hip/hip_runtime.h>
#include <stdint.h>

#define BATCH 64
#define MDIM 512
#define NDIM 512
#define KDIM 256
#define BM 128
#define BN 128
#define BK 32
#define NKSTEP 8   // KDIM / BK
#define NTILES 16  // (MDIM/BM) * (NDIM/BN)

typedef __attribute__((ext_vector_type(8))) short short8;
typedef __attribute__((ext_vector_type(4))) float f32x4;

// fp32 -> bf16 RNE via bit trick (avoids header dependencies; data is finite/normal)
__device__ __forceinline__ short f2bf(float f) {
  uint32_t u = __float_as_uint(f);
  u += 0x7FFFu + ((u >> 16) & 1u);
  return (short)(u >> 16);
}

__device__ __forceinline__ float waveRedSum(float v) {
  v += __shfl_xor(v, 32);
  v += __shfl_xor(v, 16);
  v += __shfl_xor(v, 8);
  v += __shfl_xor(v, 4);
  v += __shfl_xor(v, 2);
  v += __shfl_xor(v, 1);
  return v;
}

// One block = one 128x128 tile of one batch's cost matrix.
// Computes dot(v_i, a_j) via bf16 MFMA, rebuilds C with fp32 norms, and
// reduces {S0, CT0, rs0, cs0} partials for this tile into ws.
__global__ __launch_bounds__(256) void pot_gemm_reduce(
    const float* __restrict__ V, const float* __restrict__ A,
    float* __restrict__ part) {
  const int tile = blockIdx.x;       // 0..15
  const int b    = blockIdx.y;       // batch
  const int tm   = tile >> 2;
  const int tn   = tile & 3;

  const int tid  = threadIdx.x;      // 256 threads
  const int row  = tid >> 1;         // 0..127 : staging row
  const int half = tid & 1;          // which 16-float half of the 32-wide K slab
  const int w    = tid >> 6;         // wave 0..3
  const int lane = tid & 63;
  const int wr   = w >> 1;           // wave row 0..1  (64-row strip)
  const int wc   = w & 1;            // wave col 0..1  (64-col strip)

  __shared__ short As[2][BM][BK + 8];  // +8 bf16 pad -> 80B row stride, ~2-way banks
  __shared__ short Bs[2][BN][BK + 8];
  __shared__ float nvs[BM];
  __shared__ float nas[BN];
  __shared__ float red[4][4];

  const float* Ag = V + ((size_t)b * MDIM + (size_t)tm * BM + row) * KDIM + half * 16;
  const float* Bg = A + ((size_t)b * NDIM + (size_t)tn * BN + row) * KDIM + half * 16;

  float sqA = 0.f, sqB = 0.f;       // fp32 row-norm accumulators (exact data)
  f32x4 acc[4][4];
#pragma unroll
  for (int m = 0; m < 4; ++m)
#pragma unroll
    for (int n = 0; n < 4; ++n)
      acc[m][n] = (f32x4){0.f, 0.f, 0.f, 0.f};

  float4 ra[4], rb[4];

#define ISSUE(k)                                                            \
  {                                                                         \
    const float4* pa = reinterpret_cast<const float4*>(Ag + (k) * BK);      \
    const float4* pb = reinterpret_cast<const float4*>(Bg + (k) * BK);      \
    ra[0] = pa[0]; ra[1] = pa[1]; ra[2] = pa[2]; ra[3] = pa[3];             \
    rb[0] = pb[0]; rb[1] = pb[1]; rb[2] = pb[2]; rb[3] = pb[3];             \
  }

#define CVT4(dst, di, f)                                                    \
  {                                                                         \
    dst[(di) + 0] = f2bf((f).x); dst[(di) + 1] = f2bf((f).y);               \
    dst[(di) + 2] = f2bf((f).z); dst[(di) + 3] = f2bf((f).w);               \
  }

#define SQ4(s, f) { s += (f).x*(f).x + (f).y*(f).y + (f).z*(f).z + (f).w*(f).w; }

#define WRITE(buf)                                                          \
  {                                                                         \
    short8 w0, w1, x0, x1;                                                  \
    CVT4(w0, 0, ra[0]); CVT4(w0, 4, ra[1]);                                 \
    CVT4(w1, 0, ra[2]); CVT4(w1, 4, ra[3]);                                 \
    CVT4(x0, 0, rb[0]); CVT4(x0, 4, rb[1]);                                 \
    CVT4(x1, 0, rb[2]); CVT4(x1, 4, rb[3]);                                 \
    SQ4(sqA, ra[0]); SQ4(sqA, ra[1]); SQ4(sqA, ra[2]); SQ4(sqA, ra[3]);     \
    SQ4(sqB, rb[0]); SQ4(sqB, rb[1]); SQ4(sqB, rb[2]); SQ4(sqB, rb[3]);     \
    *reinterpret_cast<short8*>(&As[buf][row][half * 16 + 0]) = w0;          \
    *reinterpret_cast<short8*>(&As[buf][row][half * 16 + 8]) = w1;          \
    *reinterpret_cast<short8*>(&Bs[buf][row][half * 16 + 0]) = x0;          \
    *reinterpret_cast<short8*>(&Bs[buf][row][half * 16 + 8]) = x1;          \
  }

#define COMPUTE(buf)                                                        \
  {                                                                         \
    short8 af[4], bfr[4];                                                   \
    const int arow = wr * 64 + (lane & 15);                                 \
    const int brow = wc * 64 + (lane & 15);                                 \
    const int koff = (lane >> 4) * 8;                                       \
    _Pragma("unroll")                                                       \
    for (int m = 0; m < 4; ++m)                                             \
      af[m] = *reinterpret_cast<const short8*>(&As[buf][arow + m * 16][koff]); \
    _Pragma("unroll")                                                       \
    for (int n = 0; n < 4; ++n)                                             \
      bfr[n] = *reinterpret_cast<const short8*>(&Bs[buf][brow + n * 16][koff]); \
    _Pragma("unroll")                                                       \
    for (int m = 0; m < 4; ++m)                                             \
      _Pragma("unroll")                                                     \
      for (int n = 0; n < 4; ++n)                                           \
        acc[m][n] = __builtin_amdgcn_mfma_f32_16x16x32_bf16(                \
            af[m], bfr[n], acc[m][n], 0, 0, 0);                             \
  }

  // prologue: stage k=0
  ISSUE(0);
  WRITE(0);
  __syncthreads();

#pragma unroll
  for (int k = 0; k < NKSTEP; ++k) {
    const int buf = k & 1;
    if (k + 1 < NKSTEP) ISSUE(k + 1);   // loads in flight over the MFMAs
    COMPUTE(buf);
    if (k + 1 < NKSTEP) WRITE((k + 1) & 1);
    __syncthreads();
  }

  // fp32 half-norms (0.5*||row||^2) from staging accumulators
  {
    float s = sqA + __shfl_xor(sqA, 1);
    if (half == 0) nvs[row] = 0.5f * s;
    float t = sqB + __shfl_xor(sqB, 1);
    if (half == 0) nas[row] = 0.5f * t;
  }
  __syncthreads();

  // epilogue: C = hnv + hna - dot ; T = exp(-C/1000); reduce 4 scalars
  float s0p = 0.f, ctp = 0.f, rsp = 0.f, csp = 0.f;
  const int rbase = wr * 64 + (lane >> 4) * 4;
  const int cbase = wc * 64 + (lane & 15);
#pragma unroll
  for (int m = 0; m < 4; ++m) {
#pragma unroll
    for (int n = 0; n < 4; ++n) {
#pragma unroll
      for (int r = 0; r < 4; ++r) {
        const int lr = rbase + m * 16 + r;
        const int lc = cbase + n * 16;
        float Cv = nvs[lr] + nas[lc] - acc[m][n][r];
        float T = __expf(Cv * -1.0e-3f);
        s0p += T;
        ctp += Cv * T;
        rsp += (tm == 0 && lr == 0) ? T : 0.f;
        csp += (tn == 0 && lc == 0) ? T : 0.f;
      }
    }
  }

  s0p = waveRedSum(s0p);
  ctp = waveRedSum(ctp);
  rsp = waveRedSum(rsp);
  csp = waveRedSum(csp);
  if (lane == 0) { red[w][0] = s0p; red[w][1] = ctp; red[w][2] = rsp; red[w][3] = csp; }
  __syncthreads();
  if (tid == 0) {
    float* p = part + ((size_t)(b * NTILES + tile)) * 4;
    p[0] = red[0][0] + red[1][0] + red[2][0] + red[3][0];
    p[1] = red[0][1] + red[1][1] + red[2][1] + red[3][1];
    p[2] = red[0][2] + red[1][2] + red[2][2] + red[3][2];
    p[3] = red[0][3] + red[1][3] + red[2][3] + red[3][3];
  }
}

// One wave; thread b handles batch b: tree-reduce tile partials (deterministic),
// run the 10-iter scalar recurrence, mean over batches.
__global__ __launch_bounds__(64) void pot_finalize(
    const float* __restrict__ part, float* __restrict__ out) {
  const int b = threadIdx.x;  // 0..63
  float S0 = 0.f, CT = 0.f, RS = 0.f, CS = 0.f;
#pragma unroll
  for (int t = 0; t < NTILES; ++t) {
    const float* p = part + ((size_t)(b * NTILES + t)) * 4;
    S0 += p[0]; CT += p[1]; RS += p[2]; CS += p[3];
  }
  const float a0 = 1.0f / (float)MDIM;
  const float b0 = 1.0f / (float)NDIM;
  const float s  = (float)MDIM;  // min(m, n)
  float c = s / S0;
#pragma unroll
  for (int i = 0; i < 10; ++i) {
    float ka = fminf(a0 / (c * RS), 1.0f);
    float kb = fminf(b0 / (ka * c * CS), 1.0f);
    c = s * ka * kb / S0;
  }
  float D = c * CT;
  D = waveRedSum(D);
  if (b == 0) out[0] = D * (1.0f / (float)BATCH);
}

extern "C" void kernel_launch(void* const* d_in, const int* in_sizes, int n_in,
                              void* d_out, int out_size, void* d_ws, size_t ws_size,
                              hipStream_t stream) {
  const float* V = (const float*)d_in[0];   // v_emb [64,512,256] f32
  const float* A = (const float*)d_in[1];   // a_emb [64,512,256] f32
  float* out = (float*)d_out;               // 1 float
  float* part = (float*)d_ws;               // [64][16][4] f32 partials (16 KiB)

  dim3 grid(NTILES, BATCH);
  pot_gemm_reduce<<<grid, 256, 0, stream>>>(V, A, part);
  pot_finalize<<<1, 64, 0, stream>>>(part, out);
}